// Round 11
// baseline (182.990 us; speedup 1.0000x reference)
//
#include <hip/hip_runtime.h>
#include <cstddef>

#define N_IMG 8
#define B_BOX 1000
#define N_CLS 80
#define C1    81
#define K_MAX 100
#define CAND  (N_CLS * K_MAX)   // 8000
#define BPAD  1024              // padded boxes per class row

typedef unsigned long long u64;

// Exact threshold for fl32(a/b) > 0.5 under RNE:  a/b > 0.5 + 2^-25.
// (double)a > (double)b * CMP is exact: 24-bit x 25-bit significands <= 49 bits.
#define CMP_IOU (0.5 + 0x1p-25)

__device__ __forceinline__ u64 shfl_xor_u64(u64 x, int m) {
    unsigned lo = (unsigned)__shfl_xor((int)(unsigned)(x & 0xffffffffu), m);
    unsigned hi = (unsigned)__shfl_xor((int)(unsigned)(x >> 32), m);
    return ((u64)hi << 32) | lo;
}

__device__ __forceinline__ float4 decode_box(float4 rr, float4 dd) {
    // identical FP sequence to the verified kernels (contraction blocked)
    float w0 = __fadd_rn(__fsub_rn(rr.w, rr.y), 1.0f);
    float h0 = __fadd_rn(__fsub_rn(rr.z, rr.x), 1.0f);
    float x0 = __fadd_rn(rr.y, __fmul_rn(w0, 0.5f));
    float y0 = __fadd_rn(rr.x, __fmul_rn(h0, 0.5f));
    float tx = __fdiv_rn(dd.x, 10.0f);
    float ty = __fdiv_rn(dd.y, 10.0f);
    float tw = __fdiv_rn(dd.z, 5.0f);
    float th = __fdiv_rn(dd.w, 5.0f);
    float cx = __fadd_rn(__fmul_rn(tx, w0), x0);
    float cy = __fadd_rn(__fmul_rn(ty, h0), y0);
    float ww = __fmul_rn(expf(tw), w0);
    float hh = __fmul_rn(expf(th), h0);
    float xx1 = fminf(fmaxf(__fsub_rn(cx, __fmul_rn(0.5f, ww)), 0.0f), 799.0f);
    float yy1 = fminf(fmaxf(__fsub_rn(cy, __fmul_rn(0.5f, hh)), 0.0f), 799.0f);
    float xx2 = fminf(fmaxf(__fadd_rn(cx, __fmul_rn(0.5f, ww)), 0.0f), 799.0f);
    float yy2 = fminf(fmaxf(__fadd_rn(cy, __fmul_rn(0.5f, hh)), 0.0f), 799.0f);
    return make_float4(yy1, xx1, yy2, xx2);
}

// ---------------------------------------------------------------------------
// Decode/transpose (verified round 6, unchanged).
// ---------------------------------------------------------------------------
#define TILE  16
#define NTILE 63
__global__ __launch_bounds__(256) void decode_kernel(
    const float* __restrict__ rois,
    const float* __restrict__ conf,
    const float* __restrict__ deltas,
    float* __restrict__ scoreT,          // [N][80][1024]
    float* __restrict__ boxT,            // [N][80][1024][4]
    float* __restrict__ outRois)
{
    __shared__ float4 lrois[TILE];
    __shared__ float4 lbox[16][TILE + 1];
    __shared__ float  lsc[16][TILE + 1];

    const int tid  = threadIdx.x;
    const int n    = blockIdx.x / NTILE;
    const int tile = blockIdx.x % NTILE;
    const int b0   = tile * TILE;
    const float4 INERT = make_float4(1.0e9f, 1.0e9f, -1.0e9f, -1.0e9f);

    {
        int gidx = blockIdx.x * 256 + tid;
        if (gidx < N_IMG * B_BOX * 4) outRois[gidx] = rois[gidx];
    }

    if (tid < TILE) {
        int b = b0 + tid;
        lrois[tid] = (b < B_BOX) ? ((const float4*)rois)[n * B_BOX + b]
                                 : make_float4(0.f, 0.f, 0.f, 0.f);
    }
    __syncthreads();

    #pragma unroll
    for (int c0 = 0; c0 < N_CLS; c0 += 16) {
        {
            int bl = tid >> 4, ci = tid & 15;
            int b = b0 + bl, c = c0 + ci;
            float4 bx; float sc;
            if (b < B_BOX) {
                float4 dd = ((const float4*)deltas)[(n * B_BOX + b) * N_CLS + c];
                sc = conf[((size_t)(n * B_BOX + b)) * C1 + c];
                bx = decode_box(lrois[bl], dd);
            } else { bx = INERT; sc = 0.0f; }
            lbox[ci][bl] = bx; lsc[ci][bl] = sc;
        }
        __syncthreads();
        {
            int cc = tid >> 4, bl = tid & 15;
            size_t row = ((size_t)n * N_CLS + c0 + cc) * BPAD + b0 + bl;
            ((float4*)boxT)[row] = lbox[cc][bl];
            scoreT[row] = lsc[cc][bl];
        }
        __syncthreads();
    }

    if (tile == 0) {
        for (int i = tid; i < N_CLS * 16; i += 256) {
            int c = i >> 4, b = 1008 + (i & 15);
            size_t row = ((size_t)n * N_CLS + c) * BPAD + b;
            ((float4*)boxT)[row] = INERT;
            scoreT[row] = 0.0f;
        }
    }
}

// ---------------------------------------------------------------------------
// NMS: 256 threads per (image, class). Bitonic sort of positions p = 4T+t
// (verified round 10). Scan: batch-parallel greedy with ALL-PAIRS BITMASK
// in-batch resolution — row precompute is ILP-rich; the serial per-keep chain
// is just ffsll + (row>>j)&1 + ballot. Greedy order identical to the
// verified serial resolution (IoU predicate is exactly symmetric).
// ---------------------------------------------------------------------------
template <bool PRE>
__global__ __launch_bounds__(256) void nms_kernel(
    const float* __restrict__ rois,
    const float* __restrict__ conf,
    const float* __restrict__ deltas,
    const float* __restrict__ scoreT,
    const float* __restrict__ boxT,
    float* __restrict__ candScore,       // [N][CAND]
    float* __restrict__ candBox)         // [N][CAND][4]
{
    __shared__ float4 sbox[1024];
    __shared__ u64    skeyS[1024];
    __shared__ float4 sboxS[1024];
    __shared__ float4 keptB[K_MAX];
    __shared__ float  keptA[K_MAX];

    const int n = blockIdx.x / N_CLS;
    const int c = blockIdx.x % N_CLS;
    const int T = threadIdx.x;
    const float4 INERT = make_float4(1.0e9f, 1.0e9f, -1.0e9f, -1.0e9f);

    u64 e[4];

    if (PRE) {
        const size_t row = ((size_t)n * N_CLS + c) * BPAD;
        #pragma unroll
        for (int t = 0; t < 4; t++) {
            const int p = 4 * T + t;               // 64B/lane contiguous
            float4 q = ((const float4*)boxT)[row + p];
            float sc = scoreT[row + p];
            sbox[p] = q;
            unsigned sb = (sc > 0.05f) ? __float_as_uint(sc) : 0u;
            e[t] = ((u64)sb << 32) | (unsigned)(1023 - p);
        }
    } else {
        #pragma unroll
        for (int t = 0; t < 4; t++) {
            const int p = 4 * T + t;
            if (p < B_BOX) {
                float4 rr = ((const float4*)rois)[n * B_BOX + p];
                float4 dd = ((const float4*)deltas)[(n * B_BOX + p) * N_CLS + c];
                float score = conf[((size_t)(n * B_BOX + p)) * C1 + c];
                float4 q = decode_box(rr, dd);
                sbox[p] = q;
                unsigned sb = (score > 0.05f) ? __float_as_uint(score) : 0u;
                e[t] = ((u64)sb << 32) | (unsigned)(1023 - p);
            } else {
                sbox[p] = INERT;
                e[t] = (u64)(unsigned)(1023 - p);
            }
        }
    }

    // --- bitonic sort, descending (verified round 10) -----------------------
    #pragma unroll 1
    for (int k = 2; k <= 1024; k <<= 1) {
        #pragma unroll 1
        for (int j = (k >> 1); j >= 1; j >>= 1) {
            if (j >= 256) {
                #pragma unroll
                for (int t = 0; t < 4; t++) skeyS[4 * T + t] = e[t];
                __syncthreads();
                #pragma unroll
                for (int t = 0; t < 4; t++) {
                    int p = 4 * T + t;
                    u64 o = skeyS[p ^ j];
                    bool keepMin = (((p & j) == 0) == ((p & k) != 0));
                    u64 mn = (e[t] < o) ? e[t] : o;
                    u64 mx = (e[t] < o) ? o : e[t];
                    e[t] = keepMin ? mn : mx;
                }
                __syncthreads();
            } else if (j >= 4) {
                int jl = j >> 2;
                bool lower = ((T & jl) == 0);
                bool up    = (((4 * T) & k) != 0);
                bool keepMin = (lower == up);
                #pragma unroll
                for (int t = 0; t < 4; t++) {
                    u64 o = shfl_xor_u64(e[t], jl);
                    u64 mn = (e[t] < o) ? e[t] : o;
                    u64 mx = (e[t] < o) ? o : e[t];
                    e[t] = keepMin ? mn : mx;
                }
            } else if (j == 2) {
                #pragma unroll
                for (int t = 0; t < 2; t++) {
                    int p = 4 * T + t;
                    bool up = ((p & k) != 0);
                    u64 a = e[t], b = e[t + 2];
                    bool sw = up ? (a > b) : (a < b);
                    e[t]     = sw ? b : a;
                    e[t + 2] = sw ? a : b;
                }
            } else {
                #pragma unroll
                for (int t = 0; t < 4; t += 2) {
                    int p = 4 * T + t;
                    bool up = ((p & k) != 0);
                    u64 a = e[t], b = e[t + 1];
                    bool sw = up ? (a > b) : (a < b);
                    e[t]     = sw ? b : a;
                    e[t + 1] = sw ? a : b;
                }
            }
        }
    }

    #pragma unroll
    for (int t = 0; t < 4; t++) skeyS[4 * T + t] = e[t];
    __syncthreads();

    for (int p = T; p < 1024; p += 256) {
        u64 key = skeyS[p];
        int b = 1023 - (int)(unsigned)(key & 0xffffffffu);
        sboxS[p] = sbox[b];
    }
    __syncthreads();

    if (T >= 64) return;          // waves 1-3 done; scan has no barriers
    const int lane = T;

    // --- batch-parallel greedy scan with bitmask resolution ----------------
    float* myScore = candScore + (size_t)n * CAND + c * K_MAX;
    float* myBox   = candBox   + ((size_t)n * CAND + c * K_MAX) * 4;

    int cnt = 0;
    bool done = false;

    for (int t = 0; t < 16 && !done; t++) {
        const int p = t * 64 + lane;
        const u64    key = skeyS[p];
        const float4 cb  = sboxS[p];
        const bool valid = (key >> 32) != 0;
        const float carea = __fmul_rn(__fsub_rn(cb.z, cb.x), __fsub_rn(cb.w, cb.y));

        // suppression vs keeps from earlier batches (uniform LDS broadcast)
        bool sup = false;
        for (int q = 0; q < cnt; q++) {
            float4 kb = keptB[q];
            float  ka = keptA[q];
            float iy1 = fmaxf(kb.x, cb.x), ix1 = fmaxf(kb.y, cb.y);
            float iy2 = fminf(kb.z, cb.z), ix2 = fminf(kb.w, cb.w);
            float ih  = fmaxf(__fsub_rn(iy2, iy1), 0.0f);
            float iw  = fmaxf(__fsub_rn(ix2, ix1), 0.0f);
            float inter = __fmul_rn(ih, iw);
            float den = fmaxf(__fsub_rn(__fadd_rn(ka, carea), inter), 1e-8f);
            sup = sup || ((double)inter > (double)den * CMP_IOU);
        }

        // all-pairs row mask: bit o = "batch member o suppresses me".
        // IoU predicate is exactly symmetric (fmax/fadd commute bit-exactly),
        // so computing IoU(me, partner) == IoU(partner, me) of the reference.
        u64 rowm = 0;
        #pragma unroll 1
        for (int s = 1; s < 64; s++) {
            const int o = lane ^ s;
            float ox = __shfl_xor(cb.x, s);
            float oy = __shfl_xor(cb.y, s);
            float oz = __shfl_xor(cb.z, s);
            float ow = __shfl_xor(cb.w, s);
            float oa = __shfl_xor(carea, s);
            float iy1 = fmaxf(ox, cb.x), ix1 = fmaxf(oy, cb.y);
            float iy2 = fminf(oz, cb.z), ix2 = fminf(ow, cb.w);
            float ih  = fmaxf(__fsub_rn(iy2, iy1), 0.0f);
            float iw  = fmaxf(__fsub_rn(ix2, ix1), 0.0f);
            float inter = __fmul_rn(ih, iw);
            float den = fmaxf(__fsub_rn(__fadd_rn(oa, carea), inter), 1e-8f);
            bool s2 = (double)inter > (double)den * CMP_IOU;
            rowm |= (s2 ? 1ull : 0ull) << o;
        }

        const u64 vmask = __ballot(valid);
        u64 alive = vmask & __ballot(!sup);

        // serial resolution: lowest sorted position first (exact greedy order)
        while (alive != 0) {
            const int j = __ffsll(alive) - 1;
            if (lane == j) {
                myScore[cnt] = __uint_as_float((unsigned)(key >> 32));
                ((float4*)myBox)[cnt] = cb;
                keptB[cnt] = cb;
                keptA[cnt] = carea;
            }
            cnt++;
            if (cnt >= K_MAX) { done = true; break; }
            alive &= ~(1ull << j);
            if (alive != 0)
                alive &= ~__ballot((rowm >> j) & 1ull);   // removed iff j suppresses
        }

        if (vmask != ~0ull) done = true;   // sorted: rest of list is invalid
    }
    for (int q = cnt + lane; q < K_MAX; q += 64) myScore[q] = -1.0f;
}

// ---------------------------------------------------------------------------
// Top-K: exact parallel MSD radix-select (verified round 6, verbatim revert —
// R10's per-wave sub-histograms were unproven/possibly regressive).
// ---------------------------------------------------------------------------
__global__ __launch_bounds__(256) void topk_kernel(
    const float* __restrict__ candScore,
    const float* __restrict__ candBox,
    float* __restrict__ out)
{
    __shared__ unsigned U[CAND];
    __shared__ int  hist[2048];
    __shared__ int  psum[256];
    __shared__ u64  selK[K_MAX];
    __shared__ int  selQ[K_MAX];
    __shared__ int  nsel, sB, sR, cntv;

    const int n   = blockIdx.x;
    const int tid = threadIdx.x;
    const float* S = candScore + (size_t)n * CAND;

    for (int i = tid; i < CAND; i += 256) {
        float s = S[i];
        U[i] = (s > 0.0f) ? __float_as_uint(s) : 0u;
    }
    if (tid == 0) { nsel = 0; cntv = 0; }
    __syncthreads();

    u64 pref = 0;
    int r = K_MAX;

    #pragma unroll
    for (int pass = 0; pass < 4; pass++) {
        const int shift = 33 - 11 * pass;
        for (int j = tid; j < 2048; j += 256) hist[j] = 0;
        __syncthreads();

        for (int i = tid; i < CAND; i += 256) {
            u64 K = (((u64)U[i]) << 13) | (unsigned)(8191 - i);
            if ((K >> (shift + 11)) == pref)
                atomicAdd(&hist[(int)((K >> shift) & 0x7FF)], 1);
        }
        __syncthreads();

        {
            int g = 0;
            #pragma unroll
            for (int j = 0; j < 8; j++) g += hist[2047 - 8 * tid - j];
            psum[tid] = g;
        }
        __syncthreads();
        for (int off = 1; off < 256; off <<= 1) {
            int v = (tid >= off) ? psum[tid - off] : 0;
            __syncthreads();
            psum[tid] += v;
            __syncthreads();
        }
        {
            int before = (tid > 0) ? psum[tid - 1] : 0;
            if (before < r && psum[tid] >= r) {
                int acc = before;
                #pragma unroll
                for (int j = 0; j < 8; j++) {
                    int b = 2047 - 8 * tid - j;
                    int h = hist[b];
                    acc += h;
                    if (acc >= r) { sB = b; sR = r - (acc - h); break; }
                }
            }
        }
        __syncthreads();
        pref = (pref << 11) | (unsigned)sB;
        r = sR;
        __syncthreads();
    }
    const u64 T64 = pref;

    for (int i = tid; i < CAND; i += 256) {
        u64 K = (((u64)U[i]) << 13) | (unsigned)(8191 - i);
        if (K >= T64) {
            int s = atomicAdd(&nsel, 1);
            selK[s] = K; selQ[s] = i;
        }
    }
    __syncthreads();

    if (tid < K_MAX) {
        const u64 Ki = selK[tid];
        int rank = 0;
        for (int j = 0; j < K_MAX; j++) rank += (selK[j] > Ki) ? 1 : 0;

        const unsigned u = (unsigned)(Ki >> 13);
        const int q = selQ[tid];
        const bool valid = (u != 0);
        float4 bx = make_float4(0.f, 0.f, 0.f, 0.f);
        if (valid) bx = ((const float4*)candBox)[(size_t)n * CAND + q];

        ((float4*)out)[n * K_MAX + rank] = bx;
        out[N_IMG * K_MAX * 4 + n * K_MAX + rank] = valid ? __uint_as_float(u) : 0.0f;
        out[N_IMG * K_MAX * 5 + n * K_MAX + rank] = valid ? (float)(q / K_MAX) : 0.0f;
        if (valid) atomicAdd(&cntv, 1);
    }
    __syncthreads();
    if (tid == 0) out[N_IMG * K_MAX * 6 + n] = (float)cntv;
}

extern "C" void kernel_launch(void* const* d_in, const int* in_sizes, int n_in,
                              void* d_out, int out_size, void* d_ws, size_t ws_size,
                              hipStream_t stream) {
    const float* rois   = (const float*)d_in[0];   // [8][1000][4]
    const float* conf   = (const float*)d_in[1];   // [8][1000][81]
    const float* deltas = (const float*)d_in[2];   // [8][1000][320]
    float* out = (float*)d_out;                    // 36808 floats
    float* ws  = (float*)d_ws;

    float* candScore = ws;                                      // 64000 f
    float* candBox   = candScore + (size_t)N_IMG * CAND;        // 256000 f
    float* scoreT    = candBox + (size_t)N_IMG * CAND * 4;      // 655360 f
    float* boxT      = scoreT + (size_t)N_IMG * N_CLS * BPAD;   // 2621440 f
    const size_t needed = ((size_t)N_IMG * CAND * 5
                         + (size_t)N_IMG * N_CLS * BPAD * 5) * sizeof(float);

    if (ws_size >= needed) {
        decode_kernel<<<N_IMG * NTILE, 256, 0, stream>>>(
            rois, conf, deltas, scoreT, boxT, out + 4808);
        nms_kernel<true><<<N_IMG * N_CLS, 256, 0, stream>>>(
            rois, conf, deltas, scoreT, boxT, candScore, candBox);
        topk_kernel<<<N_IMG, 256, 0, stream>>>(candScore, candBox, out);
    } else {
        nms_kernel<false><<<N_IMG * N_CLS, 256, 0, stream>>>(
            rois, conf, deltas, nullptr, nullptr, candScore, candBox);
        topk_kernel<<<N_IMG, 256, 0, stream>>>(candScore, candBox, out);
        hipMemcpyAsync(out + 4808, rois,
                       (size_t)N_IMG * B_BOX * 4 * sizeof(float),
                       hipMemcpyDeviceToDevice, stream);
    }
}

// Round 12
// 174.582 us; speedup vs baseline: 1.0482x; 1.0482x over previous
//
#include <hip/hip_runtime.h>
#include <cstddef>

#define N_IMG 8
#define B_BOX 1000
#define N_CLS 80
#define C1    81
#define K_MAX 100
#define CAND  (N_CLS * K_MAX)   // 8000
#define BPAD  1024              // padded boxes per class row

typedef unsigned long long u64;

// Exact threshold for fl32(a/b) > 0.5 under RNE:  a/b > 0.5 + 2^-25.
// (double)a > (double)b * CMP is exact: 24-bit x 25-bit significands <= 49 bits.
#define CMP_IOU (0.5 + 0x1p-25)

__device__ __forceinline__ u64 shfl_xor_u64(u64 x, int m) {
    unsigned lo = (unsigned)__shfl_xor((int)(unsigned)(x & 0xffffffffu), m);
    unsigned hi = (unsigned)__shfl_xor((int)(unsigned)(x >> 32), m);
    return ((u64)hi << 32) | lo;
}

__device__ __forceinline__ float4 decode_box(float4 rr, float4 dd) {
    // identical FP sequence to the verified kernels (contraction blocked)
    float w0 = __fadd_rn(__fsub_rn(rr.w, rr.y), 1.0f);
    float h0 = __fadd_rn(__fsub_rn(rr.z, rr.x), 1.0f);
    float x0 = __fadd_rn(rr.y, __fmul_rn(w0, 0.5f));
    float y0 = __fadd_rn(rr.x, __fmul_rn(h0, 0.5f));
    float tx = __fdiv_rn(dd.x, 10.0f);
    float ty = __fdiv_rn(dd.y, 10.0f);
    float tw = __fdiv_rn(dd.z, 5.0f);
    float th = __fdiv_rn(dd.w, 5.0f);
    float cx = __fadd_rn(__fmul_rn(tx, w0), x0);
    float cy = __fadd_rn(__fmul_rn(ty, h0), y0);
    float ww = __fmul_rn(expf(tw), w0);
    float hh = __fmul_rn(expf(th), h0);
    float xx1 = fminf(fmaxf(__fsub_rn(cx, __fmul_rn(0.5f, ww)), 0.0f), 799.0f);
    float yy1 = fminf(fmaxf(__fsub_rn(cy, __fmul_rn(0.5f, hh)), 0.0f), 799.0f);
    float xx2 = fminf(fmaxf(__fadd_rn(cx, __fmul_rn(0.5f, ww)), 0.0f), 799.0f);
    float yy2 = fminf(fmaxf(__fadd_rn(cy, __fmul_rn(0.5f, hh)), 0.0f), 799.0f);
    return make_float4(yy1, xx1, yy2, xx2);
}

// ---------------------------------------------------------------------------
// Decode/transpose (verified round 6, unchanged).
// ---------------------------------------------------------------------------
#define TILE  16
#define NTILE 63
__global__ __launch_bounds__(256) void decode_kernel(
    const float* __restrict__ rois,
    const float* __restrict__ conf,
    const float* __restrict__ deltas,
    float* __restrict__ scoreT,          // [N][80][1024]
    float* __restrict__ boxT,            // [N][80][1024][4]
    float* __restrict__ outRois)
{
    __shared__ float4 lrois[TILE];
    __shared__ float4 lbox[16][TILE + 1];
    __shared__ float  lsc[16][TILE + 1];

    const int tid  = threadIdx.x;
    const int n    = blockIdx.x / NTILE;
    const int tile = blockIdx.x % NTILE;
    const int b0   = tile * TILE;
    const float4 INERT = make_float4(1.0e9f, 1.0e9f, -1.0e9f, -1.0e9f);

    {
        int gidx = blockIdx.x * 256 + tid;
        if (gidx < N_IMG * B_BOX * 4) outRois[gidx] = rois[gidx];
    }

    if (tid < TILE) {
        int b = b0 + tid;
        lrois[tid] = (b < B_BOX) ? ((const float4*)rois)[n * B_BOX + b]
                                 : make_float4(0.f, 0.f, 0.f, 0.f);
    }
    __syncthreads();

    #pragma unroll
    for (int c0 = 0; c0 < N_CLS; c0 += 16) {
        {
            int bl = tid >> 4, ci = tid & 15;
            int b = b0 + bl, c = c0 + ci;
            float4 bx; float sc;
            if (b < B_BOX) {
                float4 dd = ((const float4*)deltas)[(n * B_BOX + b) * N_CLS + c];
                sc = conf[((size_t)(n * B_BOX + b)) * C1 + c];
                bx = decode_box(lrois[bl], dd);
            } else { bx = INERT; sc = 0.0f; }
            lbox[ci][bl] = bx; lsc[ci][bl] = sc;
        }
        __syncthreads();
        {
            int cc = tid >> 4, bl = tid & 15;
            size_t row = ((size_t)n * N_CLS + c0 + cc) * BPAD + b0 + bl;
            ((float4*)boxT)[row] = lbox[cc][bl];
            scoreT[row] = lsc[cc][bl];
        }
        __syncthreads();
    }

    if (tile == 0) {
        for (int i = tid; i < N_CLS * 16; i += 256) {
            int c = i >> 4, b = 1008 + (i & 15);
            size_t row = ((size_t)n * N_CLS + c) * BPAD + b;
            ((float4*)boxT)[row] = INERT;
            scoreT[row] = 0.0f;
        }
    }
}

// ---------------------------------------------------------------------------
// NMS (verified round 10, verbatim): 256 threads per (image, class); bitonic
// sort of positions p = 4T+t; wave-0 batch-parallel greedy scan with serial
// in-batch resolution (R11's bitmask variant regressed and is removed).
// ---------------------------------------------------------------------------
template <bool PRE>
__global__ __launch_bounds__(256) void nms_kernel(
    const float* __restrict__ rois,
    const float* __restrict__ conf,
    const float* __restrict__ deltas,
    const float* __restrict__ scoreT,
    const float* __restrict__ boxT,
    float* __restrict__ candScore,       // [N][CAND]
    float* __restrict__ candBox)         // [N][CAND][4]
{
    __shared__ float4 sbox[1024];
    __shared__ u64    skeyS[1024];
    __shared__ float4 sboxS[1024];
    __shared__ float4 keptB[K_MAX];
    __shared__ float  keptA[K_MAX];

    const int n = blockIdx.x / N_CLS;
    const int c = blockIdx.x % N_CLS;
    const int T = threadIdx.x;
    const float4 INERT = make_float4(1.0e9f, 1.0e9f, -1.0e9f, -1.0e9f);

    u64 e[4];

    if (PRE) {
        const size_t row = ((size_t)n * N_CLS + c) * BPAD;
        #pragma unroll
        for (int t = 0; t < 4; t++) {
            const int p = 4 * T + t;               // 64B/lane contiguous
            float4 q = ((const float4*)boxT)[row + p];
            float sc = scoreT[row + p];
            sbox[p] = q;
            unsigned sb = (sc > 0.05f) ? __float_as_uint(sc) : 0u;
            e[t] = ((u64)sb << 32) | (unsigned)(1023 - p);
        }
    } else {
        #pragma unroll
        for (int t = 0; t < 4; t++) {
            const int p = 4 * T + t;
            if (p < B_BOX) {
                float4 rr = ((const float4*)rois)[n * B_BOX + p];
                float4 dd = ((const float4*)deltas)[(n * B_BOX + p) * N_CLS + c];
                float score = conf[((size_t)(n * B_BOX + p)) * C1 + c];
                float4 q = decode_box(rr, dd);
                sbox[p] = q;
                unsigned sb = (score > 0.05f) ? __float_as_uint(score) : 0u;
                e[t] = ((u64)sb << 32) | (unsigned)(1023 - p);
            } else {
                sbox[p] = INERT;
                e[t] = (u64)(unsigned)(1023 - p);
            }
        }
    }

    // --- bitonic sort, descending (CE(p, p^j); direction = (p&k) region) ---
    #pragma unroll 1
    for (int k = 2; k <= 1024; k <<= 1) {
        #pragma unroll 1
        for (int j = (k >> 1); j >= 1; j >>= 1) {
            if (j >= 256) {
                #pragma unroll
                for (int t = 0; t < 4; t++) skeyS[4 * T + t] = e[t];
                __syncthreads();
                #pragma unroll
                for (int t = 0; t < 4; t++) {
                    int p = 4 * T + t;
                    u64 o = skeyS[p ^ j];
                    bool keepMin = (((p & j) == 0) == ((p & k) != 0));
                    u64 mn = (e[t] < o) ? e[t] : o;
                    u64 mx = (e[t] < o) ? o : e[t];
                    e[t] = keepMin ? mn : mx;
                }
                __syncthreads();
            } else if (j >= 4) {
                int jl = j >> 2;                        // lane distance
                bool lower = ((T & jl) == 0);           // == ((p&j)==0)
                bool up    = (((4 * T) & k) != 0);      // k>=8: t bits moot
                bool keepMin = (lower == up);
                #pragma unroll
                for (int t = 0; t < 4; t++) {
                    u64 o = shfl_xor_u64(e[t], jl);
                    u64 mn = (e[t] < o) ? e[t] : o;
                    u64 mx = (e[t] < o) ? o : e[t];
                    e[t] = keepMin ? mn : mx;
                }
            } else if (j == 2) {
                #pragma unroll
                for (int t = 0; t < 2; t++) {           // pairs (0,2),(1,3)
                    int p = 4 * T + t;
                    bool up = ((p & k) != 0);
                    u64 a = e[t], b = e[t + 2];
                    bool sw = up ? (a > b) : (a < b);
                    e[t]     = sw ? b : a;
                    e[t + 2] = sw ? a : b;
                }
            } else {                                    // j == 1: (0,1),(2,3)
                #pragma unroll
                for (int t = 0; t < 4; t += 2) {
                    int p = 4 * T + t;
                    bool up = ((p & k) != 0);
                    u64 a = e[t], b = e[t + 1];
                    bool sw = up ? (a > b) : (a < b);
                    e[t]     = sw ? b : a;
                    e[t + 1] = sw ? a : b;
                }
            }
        }
    }

    #pragma unroll
    for (int t = 0; t < 4; t++) skeyS[4 * T + t] = e[t];
    __syncthreads();

    for (int p = T; p < 1024; p += 256) {
        u64 key = skeyS[p];
        int b = 1023 - (int)(unsigned)(key & 0xffffffffu);
        sboxS[p] = sbox[b];
    }
    __syncthreads();

    if (T >= 64) return;          // waves 1-3 done; scan has no barriers
    const int lane = T;

    // --- batch-parallel greedy scan (verified rounds 7-10, verbatim) -------
    float* myScore = candScore + (size_t)n * CAND + c * K_MAX;
    float* myBox   = candBox   + ((size_t)n * CAND + c * K_MAX) * 4;

    int cnt = 0;
    bool done = false;

    for (int t = 0; t < 16 && !done; t++) {
        const int p = t * 64 + lane;
        const u64    key = skeyS[p];
        const float4 cb  = sboxS[p];
        const bool valid = (key >> 32) != 0;
        const float carea = __fmul_rn(__fsub_rn(cb.z, cb.x), __fsub_rn(cb.w, cb.y));

        bool sup = false;
        for (int q = 0; q < cnt; q++) {
            float4 kb = keptB[q];
            float  ka = keptA[q];
            float iy1 = fmaxf(kb.x, cb.x), ix1 = fmaxf(kb.y, cb.y);
            float iy2 = fminf(kb.z, cb.z), ix2 = fminf(kb.w, cb.w);
            float ih  = fmaxf(__fsub_rn(iy2, iy1), 0.0f);
            float iw  = fmaxf(__fsub_rn(ix2, ix1), 0.0f);
            float inter = __fmul_rn(ih, iw);
            float den = fmaxf(__fsub_rn(__fadd_rn(ka, carea), inter), 1e-8f);
            sup = sup || ((double)inter > (double)den * CMP_IOU);
        }

        const u64 vmask = __ballot(valid);
        u64 alive = vmask & __ballot(!sup);

        while (alive != 0) {
            const int j = __ffsll(alive) - 1;
            const float bx = __int_as_float(__builtin_amdgcn_readlane(__float_as_int(cb.x), j));
            const float by = __int_as_float(__builtin_amdgcn_readlane(__float_as_int(cb.y), j));
            const float bz = __int_as_float(__builtin_amdgcn_readlane(__float_as_int(cb.z), j));
            const float bw = __int_as_float(__builtin_amdgcn_readlane(__float_as_int(cb.w), j));
            const float ba = __int_as_float(__builtin_amdgcn_readlane(__float_as_int(carea), j));

            if (lane == j) {
                myScore[cnt] = __uint_as_float((unsigned)(key >> 32));
                ((float4*)myBox)[cnt] = cb;
                keptB[cnt] = cb;
                keptA[cnt] = carea;
            }
            cnt++;
            if (cnt >= K_MAX) { done = true; break; }

            alive &= ~(1ull << j);
            if (alive != 0) {
                float iy1 = fmaxf(bx, cb.x), ix1 = fmaxf(by, cb.y);
                float iy2 = fminf(bz, cb.z), ix2 = fminf(bw, cb.w);
                float ih  = fmaxf(__fsub_rn(iy2, iy1), 0.0f);
                float iw  = fmaxf(__fsub_rn(ix2, ix1), 0.0f);
                float inter = __fmul_rn(ih, iw);
                float den = fmaxf(__fsub_rn(__fadd_rn(ba, carea), inter), 1e-8f);
                bool s2 = (double)inter > (double)den * CMP_IOU;
                alive &= ~__ballot(s2);
            }
        }

        if (vmask != ~0ull) done = true;
    }
    for (int q = cnt + lane; q < K_MAX; q += 64) myScore[q] = -1.0f;
}

// ---------------------------------------------------------------------------
// Top-K: exact parallel MSD radix-select (verified round 6, verbatim — the
// measured-fastest variant; per-wave sub-histograms (R10) and ballot
// aggregation (R8) both regressed).
// ---------------------------------------------------------------------------
__global__ __launch_bounds__(256) void topk_kernel(
    const float* __restrict__ candScore,
    const float* __restrict__ candBox,
    float* __restrict__ out)
{
    __shared__ unsigned U[CAND];
    __shared__ int  hist[2048];
    __shared__ int  psum[256];
    __shared__ u64  selK[K_MAX];
    __shared__ int  selQ[K_MAX];
    __shared__ int  nsel, sB, sR, cntv;

    const int n   = blockIdx.x;
    const int tid = threadIdx.x;
    const float* S = candScore + (size_t)n * CAND;

    for (int i = tid; i < CAND; i += 256) {
        float s = S[i];
        U[i] = (s > 0.0f) ? __float_as_uint(s) : 0u;
    }
    if (tid == 0) { nsel = 0; cntv = 0; }
    __syncthreads();

    u64 pref = 0;
    int r = K_MAX;

    #pragma unroll
    for (int pass = 0; pass < 4; pass++) {
        const int shift = 33 - 11 * pass;
        for (int j = tid; j < 2048; j += 256) hist[j] = 0;
        __syncthreads();

        for (int i = tid; i < CAND; i += 256) {
            u64 K = (((u64)U[i]) << 13) | (unsigned)(8191 - i);
            if ((K >> (shift + 11)) == pref)
                atomicAdd(&hist[(int)((K >> shift) & 0x7FF)], 1);
        }
        __syncthreads();

        {
            int g = 0;
            #pragma unroll
            for (int j = 0; j < 8; j++) g += hist[2047 - 8 * tid - j];
            psum[tid] = g;
        }
        __syncthreads();
        for (int off = 1; off < 256; off <<= 1) {
            int v = (tid >= off) ? psum[tid - off] : 0;
            __syncthreads();
            psum[tid] += v;
            __syncthreads();
        }
        {
            int before = (tid > 0) ? psum[tid - 1] : 0;
            if (before < r && psum[tid] >= r) {
                int acc = before;
                #pragma unroll
                for (int j = 0; j < 8; j++) {
                    int b = 2047 - 8 * tid - j;
                    int h = hist[b];
                    acc += h;
                    if (acc >= r) { sB = b; sR = r - (acc - h); break; }
                }
            }
        }
        __syncthreads();
        pref = (pref << 11) | (unsigned)sB;
        r = sR;
        __syncthreads();
    }
    const u64 T64 = pref;

    for (int i = tid; i < CAND; i += 256) {
        u64 K = (((u64)U[i]) << 13) | (unsigned)(8191 - i);
        if (K >= T64) {
            int s = atomicAdd(&nsel, 1);
            selK[s] = K; selQ[s] = i;
        }
    }
    __syncthreads();

    if (tid < K_MAX) {
        const u64 Ki = selK[tid];
        int rank = 0;
        for (int j = 0; j < K_MAX; j++) rank += (selK[j] > Ki) ? 1 : 0;

        const unsigned u = (unsigned)(Ki >> 13);
        const int q = selQ[tid];
        const bool valid = (u != 0);
        float4 bx = make_float4(0.f, 0.f, 0.f, 0.f);
        if (valid) bx = ((const float4*)candBox)[(size_t)n * CAND + q];

        ((float4*)out)[n * K_MAX + rank] = bx;
        out[N_IMG * K_MAX * 4 + n * K_MAX + rank] = valid ? __uint_as_float(u) : 0.0f;
        out[N_IMG * K_MAX * 5 + n * K_MAX + rank] = valid ? (float)(q / K_MAX) : 0.0f;
        if (valid) atomicAdd(&cntv, 1);
    }
    __syncthreads();
    if (tid == 0) out[N_IMG * K_MAX * 6 + n] = (float)cntv;
}

extern "C" void kernel_launch(void* const* d_in, const int* in_sizes, int n_in,
                              void* d_out, int out_size, void* d_ws, size_t ws_size,
                              hipStream_t stream) {
    const float* rois   = (const float*)d_in[0];   // [8][1000][4]
    const float* conf   = (const float*)d_in[1];   // [8][1000][81]
    const float* deltas = (const float*)d_in[2];   // [8][1000][320]
    float* out = (float*)d_out;                    // 36808 floats
    float* ws  = (float*)d_ws;

    float* candScore = ws;                                      // 64000 f
    float* candBox   = candScore + (size_t)N_IMG * CAND;        // 256000 f
    float* scoreT    = candBox + (size_t)N_IMG * CAND * 4;      // 655360 f
    float* boxT      = scoreT + (size_t)N_IMG * N_CLS * BPAD;   // 2621440 f
    const size_t needed = ((size_t)N_IMG * CAND * 5
                         + (size_t)N_IMG * N_CLS * BPAD * 5) * sizeof(float);

    if (ws_size >= needed) {
        decode_kernel<<<N_IMG * NTILE, 256, 0, stream>>>(
            rois, conf, deltas, scoreT, boxT, out + 4808);
        nms_kernel<true><<<N_IMG * N_CLS, 256, 0, stream>>>(
            rois, conf, deltas, scoreT, boxT, candScore, candBox);
        topk_kernel<<<N_IMG, 256, 0, stream>>>(candScore, candBox, out);
    } else {
        nms_kernel<false><<<N_IMG * N_CLS, 256, 0, stream>>>(
            rois, conf, deltas, nullptr, nullptr, candScore, candBox);
        topk_kernel<<<N_IMG, 256, 0, stream>>>(candScore, candBox, out);
        hipMemcpyAsync(out + 4808, rois,
                       (size_t)N_IMG * B_BOX * 4 * sizeof(float),
                       hipMemcpyDeviceToDevice, stream);
    }
}